// Round 5
// baseline (348.058 us; speedup 1.0000x reference)
//
#include <hip/hip_runtime.h>

typedef unsigned short u16;
typedef unsigned int u32;
typedef short s16x8 __attribute__((ext_vector_type(8)));
typedef float f32x4 __attribute__((ext_vector_type(4)));

#define AS1 __attribute__((address_space(1)))
#define AS3 __attribute__((address_space(3)))

// B=2, SQ=SKV=2048, H=1024, NH=16, HD=64
#define LOG2E 1.4426950408889634f

__device__ __forceinline__ u16 f2bf(float f) {
  unsigned u = __float_as_uint(f);
  u += 0x7fffu + ((u >> 16) & 1u);      // RNE
  return (u16)(u >> 16);
}
__device__ __forceinline__ float bf2f(u16 b) {
  return __uint_as_float(((unsigned)b) << 16);
}
__device__ __forceinline__ u32 cvtpk(float lo, float hi) {  // bf16(lo) | bf16(hi)<<16, RNE
  u32 r;
  asm("v_cvt_pk_bf16_f32 %0, %1, %2" : "=v"(r) : "v"(lo), "v"(hi));
  return r;
}
__device__ __forceinline__ void gld16(const void* g, void* l) {
  __builtin_amdgcn_global_load_lds((const AS1 unsigned int*)g,
                                   (AS3 unsigned int*)l, 16, 0, 0);
}

// ---------------- prep: fp32 -> bf16 (+ additive mask, pre-scaled by log2e) ----------------
__global__ __launch_bounds__(256) void prep_kernel(
    const float* __restrict__ qs, const float* __restrict__ kvs, const float* __restrict__ mk,
    const float* __restrict__ wq, const float* __restrict__ wk, const float* __restrict__ wv,
    const float* __restrict__ wo,
    u16* __restrict__ q_bf, u16* __restrict__ kv_bf, u16* __restrict__ am_bf,
    u16* __restrict__ wq_bf, u16* __restrict__ wk_bf, u16* __restrict__ wv_bf,
    u16* __restrict__ wo_bf)
{
  const int stride = gridDim.x * blockDim.x;
  const float mscale = -10000.f * LOG2E;
  for (int v = blockIdx.x * blockDim.x + threadIdx.x; v < 5242880; v += stride) {
    const float* s; u16* d; int off; bool ismask = false;
    if (v < 1048576)      { s = qs;  d = q_bf;  off = v; }
    else if (v < 2097152) { s = kvs; d = kv_bf; off = v - 1048576; }
    else if (v < 2359296) { s = wq;  d = wq_bf; off = v - 2097152; }
    else if (v < 2621440) { s = wk;  d = wk_bf; off = v - 2359296; }
    else if (v < 2883584) { s = wv;  d = wv_bf; off = v - 2621440; }
    else if (v < 3145728) { s = wo;  d = wo_bf; off = v - 2883584; }
    else                  { s = mk;  d = am_bf; off = v - 3145728; ismask = true; }
    float4 f = ((const float4*)s)[off];
    if (ismask) {
      f.x = (1.f - f.x) * mscale; f.y = (1.f - f.y) * mscale;
      f.z = (1.f - f.z) * mscale; f.w = (1.f - f.w) * mscale;
    }
    uint2 o;
    o.x = cvtpk(f.x, f.y);
    o.y = cvtpk(f.z, f.w);
    ((uint2*)d)[off] = o;
  }
}

// ---------------- mask tile flags: bit kt set if 128q x 64kv tile is all (-)0 ----------------
__global__ __launch_bounds__(256) void flag_kernel(const u16* __restrict__ am,
                                                   u32* __restrict__ flags)
{
  const int fid = blockIdx.x;           // [0,1024) = b*512 + qt*32 + kt
  const int kt = fid & 31, qt = (fid >> 5) & 15, b = fid >> 9;
  const int t = threadIdx.x;
  const int row = t >> 1, half = t & 1;
  const u16* p = am + ((size_t)(b * 2048 + qt * 128 + row)) * 2048 + kt * 64 + half * 32;
  const uint4 v0 = *(const uint4*)p;
  const uint4 v1 = *(const uint4*)(p + 16);
  const u32 acc = v0.x | v0.y | v0.z | v0.w | v1.x | v1.y | v1.z | v1.w;
  const bool z = (acc & 0x7fff7fffu) == 0;   // bf16 +/-0 in both halves
  const bool wz = __all(z);
  __shared__ int ok[4];
  if ((t & 63) == 0) ok[t >> 6] = wz;
  __syncthreads();
  if (t == 0 && ok[0] && ok[1] && ok[2] && ok[3])
    atomicOr(&flags[(b << 4) + qt], 1u << kt);
}

// ---------------- 128x128 bf16 NT GEMM, ring-3, raw barriers + counted vmcnt ----------------
template<int EPI>
__device__ __forceinline__ void gemm_body(
    const u16* __restrict__ A, const u16* __restrict__ W, const float* __restrict__ bias,
    void* __restrict__ outp, float alpha, int m0, int n0)
{
  __shared__ u16 As[3][4096], Bs[3][4096];
  const int tid = threadIdx.x, wave = tid >> 6, lane = tid & 63;
  const int l15 = lane & 15, l4 = lane >> 4;
  const int wr = wave >> 1, wc = wave & 1;

  // staging: 4-lane clusters cover one 64B row segment; logical k-octet XOR-swizzled
  const int srow = wave * 16 + (lane >> 2);
  const int sslot = ((lane & 3) ^ ((lane >> 3) & 3)) * 8;
  const u16* aS0 = A + (size_t)(m0 + srow) * 1024 + sslot;
  const u16* aS1 = A + (size_t)(m0 + 64 + srow) * 1024 + sslot;
  const u16* bS0 = W + (size_t)(n0 + srow) * 1024 + sslot;
  const u16* bS1 = W + (size_t)(n0 + 64 + srow) * 1024 + sslot;
  const int dOff0 = wave * 512, dOff1 = 2048 + wave * 512;

  // frag read offsets (elements), swizzle matches the staged permutation
  const int fswz = ((l15 >> 1) & 3);
  const int afBase = (wr * 64 + l15) * 32 + ((l4 ^ fswz) * 8);
  const int bfBase = (wc * 64 + l15) * 32 + ((l4 ^ fswz) * 8);

  f32x4 acc[4][4] = {};

  auto stage = [&](int buf, int kt) {
    const int ko = kt * 32;
    gld16(aS0 + ko, &As[buf][dOff0]);
    gld16(aS1 + ko, &As[buf][dOff1]);
    gld16(bS0 + ko, &Bs[buf][dOff0]);
    gld16(bS1 + ko, &Bs[buf][dOff1]);
  };

  stage(0, 0);
  stage(1, 1);

  int cb = 0;
  for (int kt = 0; kt < 32; ++kt) {
    // retire this step's buffer (next step's prefetch stays in flight), raw barrier
    if (kt < 31) asm volatile("s_waitcnt vmcnt(4)" ::: "memory");
    else         asm volatile("s_waitcnt vmcnt(0)" ::: "memory");
    __builtin_amdgcn_s_barrier();
    asm volatile("" ::: "memory");
    if (kt < 30) {
      int sb = cb + 2; if (sb >= 3) sb -= 3;
      stage(sb, kt + 2);
    }
    s16x8 af[4], bf[4];
    #pragma unroll
    for (int m = 0; m < 4; ++m) af[m] = *(const s16x8*)&As[cb][afBase + m * 512];
    #pragma unroll
    for (int n = 0; n < 4; ++n) bf[n] = *(const s16x8*)&Bs[cb][bfBase + n * 512];
    #pragma unroll
    for (int m = 0; m < 4; ++m)
      #pragma unroll
      for (int n = 0; n < 4; ++n)
        acc[m][n] = __builtin_amdgcn_mfma_f32_16x16x32_bf16(af[m], bf[n], acc[m][n], 0, 0, 0);
    asm volatile("" ::: "memory");
    cb = (cb + 1 == 3) ? 0 : cb + 1;
  }

  #pragma unroll
  for (int n = 0; n < 4; ++n) {
    const int col = n0 + wc * 64 + n * 16 + l15;
    #pragma unroll
    for (int m = 0; m < 4; ++m) {
      #pragma unroll
      for (int r = 0; r < 4; ++r) {
        const int row = m0 + wr * 64 + m * 16 + l4 * 4 + r;
        if constexpr (EPI == 0) {
          const float val = (acc[m][n][r] + (bias ? bias[col] : 0.f)) * alpha;
          const int bb = row >> 11, ss = row & 2047, hh = col >> 6, dd = col & 63;
          ((u16*)outp)[(((size_t)(bb * 16 + hh)) * 2048 + ss) * 64 + dd] = f2bf(val);
        } else if constexpr (EPI == 1) {
          ((float*)outp)[(size_t)row * 1024 + col] = acc[m][n][r] + (bias ? bias[col] : 0.f);
        } else {  // EPI==2: V^T out [B*NH][64][2048]
          const float val = acc[m][n][r] + bias[row];
          const int hh = row >> 6, dd = row & 63, bb = col >> 11, ss = col & 2047;
          ((u16*)outp)[(((size_t)(bb * 16 + hh)) * 64 + dd) * 2048 + ss] = f2bf(val);
        }
      }
    }
  }
}

// M=4096,N=1024: XCD (bid&7) owns 4 m-bands x all n -> A-band 1MB + B 2MB = 3MB L2-resident
__global__ __launch_bounds__(256) void gemm_nt0(
    const u16* __restrict__ A, const u16* __restrict__ W, const float* __restrict__ bias,
    u16* __restrict__ out, float alpha)
{
  const int bid = blockIdx.x;
  const int swz = (bid & 7) * 32 + (bid >> 3);
  gemm_body<0>(A, W, bias, out, alpha, (swz >> 3) * 128, (swz & 7) * 128);
}

// V^T = Wv * KV^T (M=1024,N=4096): XCD owns 4 n-panels (1MB) + full Wv (2MB) = 3MB
__global__ __launch_bounds__(256) void gemm_vT(
    const u16* __restrict__ wvb, const u16* __restrict__ kvbf, const float* __restrict__ bv,
    u16* __restrict__ Vt)
{
  const int bid = blockIdx.x;
  const int m0 = (bid >> 5) * 128;
  const int n0 = ((bid & 7) + ((bid >> 3) & 3) * 8) * 128;
  gemm_body<2>(wvb, kvbf, bv, Vt, 1.0f, m0, n0);
}

__global__ __launch_bounds__(256) void gemm_fin(
    const u16* __restrict__ ctx, const u16* __restrict__ wob,
    const float* __restrict__ bo, float* __restrict__ out)
{
  const int bid = blockIdx.x;
  const int swz = (bid & 7) * 32 + (bid >> 3);
  gemm_body<1>(ctx, wob, bo, out, 1.0f, (swz >> 3) * 128, (swz & 7) * 128);
}

// ---------------- flash attention: dbuf-2, raw barriers, log2 softmax, mask-skip ----------------
// grid 512 XCD-chunked (4 heads/XCD). 128 q/block, 32 q/wave (2 groups of 16).
// S^T = K*Q^T (kv lane-local). Per-tile scalar flag bit skips all mask work.
__global__ __launch_bounds__(256) void attn_kernel(
    const u16* __restrict__ Qh, const u16* __restrict__ Kh,
    const u16* __restrict__ Vt, const u16* __restrict__ am,
    const u32* __restrict__ fbitsp, u16* __restrict__ ctx)
{
  __shared__ u16 Ks[2][4096];        // [64 kv][64 d] swizzled
  __shared__ u16 Vs[2][4096];        // [64 d][64 kv] swizzled
  __shared__ u16 Pl[4][2][1024];     // per wave per g: [16 q][64 kv] swizzled
  const int tid = threadIdx.x, wave = tid >> 6, lane = tid & 63;
  const int l15 = lane & 15, l4 = lane >> 4;
  const int x7 = l15 & 7;
  const int bid = blockIdx.x;
  const int pos = (bid & 7) * 64 + (bid >> 3);   // XCD-chunked (512 = 8*64)
  const int hh = pos >> 4, qt = pos & 15;
  const int b = hh >> 4, h = hh & 15;
  const int q0 = qt * 128;
  const u16* Qb = Qh + (size_t)hh * 2048 * 64;
  const u16* Kb = Kh + (size_t)hh * 2048 * 64;
  const u16* Vb = Vt + (size_t)hh * 64 * 2048;
  const u32 fbits = fbitsp[(b << 4) + qt];

  // Q B-frags (col=q=l15, k=d=l4*8+j); 1/8*log2e folded at projection
  s16x8 qf[2][2];
  const u16* amrow[2];
  #pragma unroll
  for (int g = 0; g < 2; ++g) {
    const int qrow = q0 + wave * 32 + g * 16 + l15;
    qf[g][0] = *(const s16x8*)(Qb + (size_t)qrow * 64 + l4 * 8);
    qf[g][1] = *(const s16x8*)(Qb + (size_t)qrow * 64 + 32 + l4 * 8);
    amrow[g] = am + ((size_t)b * 2048 + qrow) * 2048;
  }

  // staging: 8-lane clusters cover one 128B row; slot XOR-swizzled via global src
  const int sr = wave * 16 + (lane >> 3);
  const int ss = ((lane & 7) ^ ((lane >> 3) & 7)) * 8;
  const u16* kS0 = Kb + (size_t)sr * 64 + ss;
  const u16* kS1 = Kb + (size_t)(sr + 8) * 64 + ss;
  const u16* vS0 = Vb + (size_t)sr * 2048 + ss;
  const u16* vS1 = Vb + (size_t)(sr + 8) * 2048 + ss;
  const int kd0 = wave * 1024, kd1 = kd0 + 512;

  auto stage = [&](int buf, int kt) {
    const int kv0 = kt * 64;
    gld16(kS0 + (size_t)kv0 * 64, &Ks[buf][kd0]);
    gld16(kS1 + (size_t)kv0 * 64, &Ks[buf][kd1]);
    gld16(vS0 + kv0, &Vs[buf][kd0]);
    gld16(vS1 + kv0, &Vs[buf][kd1]);
  };

  f32x4 of[2][4] = {};
  float m_run[2] = {-1e30f, -1e30f}, l_run[2] = {0.f, 0.f};

  stage(0, 0);
  asm volatile("s_waitcnt vmcnt(0)" ::: "memory");
  __builtin_amdgcn_s_barrier();
  asm volatile("" ::: "memory");

  int cur = 0;
  for (int kt = 0; kt < 32; ++kt) {
    if (kt < 31) stage(cur ^ 1, kt + 1);
    const int kv0 = kt * 64;
    const bool skip = (fbits >> kt) & 1u;

    ushort4 mk4[2][4];
    if (!skip) {
      #pragma unroll
      for (int g = 0; g < 2; ++g)
        #pragma unroll
        for (int nf = 0; nf < 4; ++nf)
          mk4[g][nf] = *(const ushort4*)(amrow[g] + kv0 + nf * 16 + l4 * 4);
    }

    // S^T = K * Q^T : lane holds q=l15, kv_local = nf*16 + l4*4 + r
    f32x4 sf[2][4];
    __builtin_amdgcn_s_setprio(1);
    #pragma unroll
    for (int nf = 0; nf < 4; ++nf) {
      const s16x8 ka0 = *(const s16x8*)&Ks[cur][nf * 1024 + l15 * 64 + ((l4 ^ x7) * 8)];
      const s16x8 ka1 = *(const s16x8*)&Ks[cur][nf * 1024 + l15 * 64 + (((4 + l4) ^ x7) * 8)];
      #pragma unroll
      for (int g = 0; g < 2; ++g) {
        f32x4 s = {0.f, 0.f, 0.f, 0.f};
        s = __builtin_amdgcn_mfma_f32_16x16x32_bf16(ka0, qf[g][0], s, 0, 0, 0);
        s = __builtin_amdgcn_mfma_f32_16x16x32_bf16(ka1, qf[g][1], s, 0, 0, 0);
        sf[g][nf] = s;
      }
    }
    __builtin_amdgcn_s_setprio(0);

    // online softmax per q-group (log2 domain, defer-max THR = 8 nats)
    #pragma unroll
    for (int g = 0; g < 2; ++g) {
      float tmax = -1e30f;
      #pragma unroll
      for (int nf = 0; nf < 4; ++nf)
        #pragma unroll
        for (int r = 0; r < 4; ++r) {
          float sv = sf[g][nf][r];
          if (!skip) sv += bf2f(((const u16*)&mk4[g][nf])[r]);
          sf[g][nf][r] = sv;
          tmax = fmaxf(tmax, sv);
        }
      tmax = fmaxf(tmax, __shfl_xor(tmax, 16));
      tmax = fmaxf(tmax, __shfl_xor(tmax, 32));

      const float mOld = m_run[g];
      float mn = mOld;
      if (!__all(tmax <= mOld + 11.54f)) {        // rescale path
        mn = fmaxf(mOld, tmax);
        const float sc = exp2f(mOld - mn);
        m_run[g] = mn;
        l_run[g] *= sc;
        float sq[4];
        #pragma unroll
        for (int r = 0; r < 4; ++r) sq[r] = __shfl(sc, l4 * 4 + r);
        #pragma unroll
        for (int nd = 0; nd < 4; ++nd)
          #pragma unroll
          for (int r = 0; r < 4; ++r) of[g][nd][r] *= sq[r];
      }

      float psum = 0.f;
      u32* pw = (u32*)&Pl[wave][g][0];
      #pragma unroll
      for (int nf = 0; nf < 4; ++nf) {
        const float p0 = exp2f(sf[g][nf][0] - mn), p1 = exp2f(sf[g][nf][1] - mn);
        const float p2 = exp2f(sf[g][nf][2] - mn), p3 = exp2f(sf[g][nf][3] - mn);
        psum += (p0 + p1) + (p2 + p3);
        u32* w = pw + l15 * 32 + (((nf * 2 + (l4 >> 1)) ^ x7) * 4) + (l4 & 1) * 2;
        w[0] = cvtpk(p0, p1);
        w[1] = cvtpk(p2, p3);
      }
      psum += __shfl_xor(psum, 16);
      psum += __shfl_xor(psum, 32);
      l_run[g] += psum;
    }

    // O += P * V
    __builtin_amdgcn_s_setprio(1);
    #pragma unroll
    for (int kh = 0; kh < 2; ++kh) {
      s16x8 pa[2];
      #pragma unroll
      for (int g = 0; g < 2; ++g)
        pa[g] = *(const s16x8*)&Pl[wave][g][l15 * 64 + (((kh * 4 + l4) ^ x7) * 8)];
      #pragma unroll
      for (int nd = 0; nd < 4; ++nd) {
        const s16x8 vb = *(const s16x8*)&Vs[cur][nd * 1024 + l15 * 64 + (((kh * 4 + l4) ^ x7) * 8)];
        #pragma unroll
        for (int g = 0; g < 2; ++g)
          of[g][nd] = __builtin_amdgcn_mfma_f32_16x16x32_bf16(pa[g], vb, of[g][nd], 0, 0, 0);
      }
    }
    __builtin_amdgcn_s_setprio(0);

    if (kt < 31) {
      asm volatile("s_waitcnt vmcnt(0)" ::: "memory");
      __builtin_amdgcn_s_barrier();
      asm volatile("" ::: "memory");
    }
    cur ^= 1;
  }

  // epilogue: normalize + write ctx [B][S][H] bf16
  #pragma unroll
  for (int g = 0; g < 2; ++g) {
    const float inv = 1.f / l_run[g];
    float invq[4];
    #pragma unroll
    for (int r = 0; r < 4; ++r) invq[r] = __shfl(inv, l4 * 4 + r);
    #pragma unroll
    for (int r = 0; r < 4; ++r) {
      const int qg = q0 + wave * 32 + g * 16 + l4 * 4 + r;
      const size_t rowbase = ((size_t)b * 2048 + qg) * 1024 + h * 64;
      #pragma unroll
      for (int nd = 0; nd < 4; ++nd)
        ctx[rowbase + nd * 16 + l15] = f2bf(of[g][nd][r] * invq[r]);
    }
  }
}

// ---------------- launcher ----------------
extern "C" void kernel_launch(void* const* d_in, const int* in_sizes, int n_in,
                              void* d_out, int out_size, void* d_ws, size_t ws_size,
                              hipStream_t stream)
{
  const float* qs = (const float*)d_in[0];
  const float* kvs = (const float*)d_in[1];
  const float* mk = (const float*)d_in[2];
  const float* Wq = (const float*)d_in[3];
  const float* bq = (const float*)d_in[4];
  const float* Wk = (const float*)d_in[5];
  const float* Wv = (const float*)d_in[6];
  const float* bv = (const float*)d_in[7];
  const float* Wo = (const float*)d_in[8];
  const float* bo = (const float*)d_in[9];
  float* out = (float*)d_out;

  char* ws = (char*)d_ws;
  u16* q_bf  = (u16*)(ws + 0);
  u16* kv_bf = (u16*)(ws + 8388608);
  u16* wq_bf = (u16*)(ws + 16777216);
  u16* wk_bf = (u16*)(ws + 18874368);
  u16* wv_bf = (u16*)(ws + 20971520);
  u16* wo_bf = (u16*)(ws + 23068672);
  u16* am_bf = (u16*)(ws + 25165824);
  u16* Qhp   = (u16*)(ws + 41943040);   // [B*NH][2048][64]
  u16* Khp   = (u16*)(ws + 50331648);   // [B*NH][2048][64]
  u16* Vtp   = (u16*)(ws + 58720256);   // [B*NH][64][2048]  (pre-transposed)
  u16* ctxp  = (u16*)(ws + 67108864);   // [B][2048][1024]
  u32* flagsp = (u32*)wq_bf;            // 128 B; wq_bf is dead after gemm_nt0(q)

  prep_kernel<<<dim3(2048), dim3(256), 0, stream>>>(
      qs, kvs, mk, Wq, Wk, Wv, Wo, q_bf, kv_bf, am_bf, wq_bf, wk_bf, wv_bf, wo_bf);

  // sequential projection GEMMs: per-XCD working set 3MB -> L2-resident staging
  gemm_nt0<<<dim3(256), dim3(256), 0, stream>>>(q_bf, wq_bf, bq, Qhp, 0.125f * LOG2E);
  gemm_nt0<<<dim3(256), dim3(256), 0, stream>>>(kv_bf, wk_bf, nullptr, Khp, 1.0f);
  gemm_vT <<<dim3(256), dim3(256), 0, stream>>>(wv_bf, kv_bf, bv, Vtp);

  hipMemsetAsync(flagsp, 0, 128, stream);
  flag_kernel<<<dim3(1024), dim3(256), 0, stream>>>(am_bf, flagsp);

  attn_kernel<<<dim3(512), dim3(256), 0, stream>>>(Qhp, Khp, Vtp, am_bf, flagsp, ctxp);

  gemm_fin<<<dim3(256), dim3(256), 0, stream>>>(ctxp, wo_bf, bo, out);
}

// Round 6
// 284.336 us; speedup vs baseline: 1.2241x; 1.2241x over previous
//
#include <hip/hip_runtime.h>

typedef unsigned short u16;
typedef unsigned char u8;
typedef unsigned int u32;
typedef short s16x8 __attribute__((ext_vector_type(8)));
typedef float f32x4 __attribute__((ext_vector_type(4)));

#define AS1 __attribute__((address_space(1)))
#define AS3 __attribute__((address_space(3)))

// B=2, SQ=SKV=2048, H=1024, NH=16, HD=64
#define LOG2E 1.4426950408889634f

__device__ __forceinline__ u16 f2bf(float f) {
  unsigned u = __float_as_uint(f);
  u += 0x7fffu + ((u >> 16) & 1u);      // RNE
  return (u16)(u >> 16);
}
__device__ __forceinline__ float bf2f(u16 b) {
  return __uint_as_float(((unsigned)b) << 16);
}
__device__ __forceinline__ u32 cvtpk(float lo, float hi) {  // bf16(lo) | bf16(hi)<<16, RNE
  u32 r;
  asm("v_cvt_pk_bf16_f32 %0, %1, %2" : "=v"(r) : "v"(lo), "v"(hi));
  return r;
}
__device__ __forceinline__ void gld16(const void* g, void* l) {
  __builtin_amdgcn_global_load_lds((const AS1 unsigned int*)g,
                                   (AS3 unsigned int*)l, 16, 0, 0);
}

// ---------------- prep: fp32 -> bf16 (+ additive mask, pre-scaled by log2e) ----------------
__global__ __launch_bounds__(256) void prep_kernel(
    const float* __restrict__ qs, const float* __restrict__ kvs, const float* __restrict__ mk,
    const float* __restrict__ wq, const float* __restrict__ wk, const float* __restrict__ wv,
    const float* __restrict__ wo,
    u16* __restrict__ q_bf, u16* __restrict__ kv_bf, u16* __restrict__ am_bf,
    u16* __restrict__ wq_bf, u16* __restrict__ wk_bf, u16* __restrict__ wv_bf,
    u16* __restrict__ wo_bf)
{
  const int stride = gridDim.x * blockDim.x;
  const float mscale = -10000.f * LOG2E;
  for (int v = blockIdx.x * blockDim.x + threadIdx.x; v < 5242880; v += stride) {
    const float* s; u16* d; int off; bool ismask = false;
    if (v < 1048576)      { s = qs;  d = q_bf;  off = v; }
    else if (v < 2097152) { s = kvs; d = kv_bf; off = v - 1048576; }
    else if (v < 2359296) { s = wq;  d = wq_bf; off = v - 2097152; }
    else if (v < 2621440) { s = wk;  d = wk_bf; off = v - 2359296; }
    else if (v < 2883584) { s = wv;  d = wv_bf; off = v - 2621440; }
    else if (v < 3145728) { s = wo;  d = wo_bf; off = v - 2883584; }
    else                  { s = mk;  d = am_bf; off = v - 3145728; ismask = true; }
    float4 f = ((const float4*)s)[off];
    if (ismask) {
      f.x = (1.f - f.x) * mscale; f.y = (1.f - f.y) * mscale;
      f.z = (1.f - f.z) * mscale; f.w = (1.f - f.w) * mscale;
    }
    uint2 o;
    o.x = cvtpk(f.x, f.y);
    o.y = cvtpk(f.z, f.w);
    ((uint2*)d)[off] = o;
  }
}

// ---------------- mask tile flags: byte fid = 1 if 128q x 64kv tile is all (-)0 ----------------
__global__ __launch_bounds__(256) void flag_kernel(const u16* __restrict__ am,
                                                   u8* __restrict__ flags)
{
  const int fid = blockIdx.x;           // [0,1024) = b*512 + qt*32 + kt
  const int kt = fid & 31, qt = (fid >> 5) & 15, b = fid >> 9;
  const int t = threadIdx.x;
  const int row = t >> 1, half = t & 1;
  const u16* p = am + ((size_t)(b * 2048 + qt * 128 + row)) * 2048 + kt * 64 + half * 32;
  const uint4 v0 = *(const uint4*)p;
  const uint4 v1 = *(const uint4*)(p + 16);
  const u32 acc = v0.x | v0.y | v0.z | v0.w | v1.x | v1.y | v1.z | v1.w;
  const bool z = (acc & 0x7fff7fffu) == 0;   // bf16 +/-0 in both halves
  const bool wz = __all(z);
  __shared__ int ok[4];
  if ((t & 63) == 0) ok[t >> 6] = wz;
  __syncthreads();
  if (t == 0) flags[fid] = (ok[0] & ok[1] & ok[2] & ok[3]) ? 1 : 0;
}

// ---------- 128x128 bf16 NT GEMM, 8 waves (512 thr), ring-3 counted vmcnt ----------
// wave w -> 32x64 sub-tile (wr=w>>1 rows, wc=w&1 cols): 8 MFMA + 6 ds_read_b128/step.
// Staging: 1 gld16/wave for A + 1 for B per step (16 rows x 64B each, quad-coalesced,
// k-octet XOR-swizzled via pre-swizzled global source; reads swizzle-matched).
template<int EPI>
__device__ __forceinline__ void gemm_body(
    const u16* __restrict__ A, const u16* __restrict__ W, const float* __restrict__ bias,
    void* __restrict__ outp, float alpha, int m0, int n0)
{
  __shared__ u16 As[3][4096], Bs[3][4096];
  const int tid = threadIdx.x, wave = tid >> 6, lane = tid & 63;
  const int l15 = lane & 15, l4 = lane >> 4;
  const int wr = wave >> 1, wc = wave & 1;

  const int srow = wave * 16 + (lane >> 2);
  const int soct = ((lane & 3) ^ ((lane >> 3) & 3)) * 8;
  const u16* aS = A + (size_t)(m0 + srow) * 1024 + soct;
  const u16* bS = W + (size_t)(n0 + srow) * 1024 + soct;
  const int dOff = wave * 512;

  const int fswz = (l15 >> 1) & 3;
  const int afBase = (wr * 32 + l15) * 32 + ((l4 ^ fswz) * 8);
  const int bfBase = (wc * 64 + l15) * 32 + ((l4 ^ fswz) * 8);

  f32x4 acc[2][4] = {};

  auto stage = [&](int buf, int kt) {
    const int ko = kt * 32;
    gld16(aS + ko, &As[buf][dOff]);
    gld16(bS + ko, &Bs[buf][dOff]);
  };

  stage(0, 0);
  stage(1, 1);

  int cb = 0;
  for (int kt = 0; kt < 32; ++kt) {
    if (kt < 31) asm volatile("s_waitcnt vmcnt(2)" ::: "memory");
    else         asm volatile("s_waitcnt vmcnt(0)" ::: "memory");
    __builtin_amdgcn_s_barrier();
    asm volatile("" ::: "memory");
    if (kt < 30) {
      int sb = cb + 2; if (sb >= 3) sb -= 3;
      stage(sb, kt + 2);
    }
    s16x8 af[2], bf[4];
    #pragma unroll
    for (int m = 0; m < 2; ++m) af[m] = *(const s16x8*)&As[cb][afBase + m * 512];
    #pragma unroll
    for (int n = 0; n < 4; ++n) bf[n] = *(const s16x8*)&Bs[cb][bfBase + n * 512];
    #pragma unroll
    for (int m = 0; m < 2; ++m)
      #pragma unroll
      for (int n = 0; n < 4; ++n)
        acc[m][n] = __builtin_amdgcn_mfma_f32_16x16x32_bf16(af[m], bf[n], acc[m][n], 0, 0, 0);
    asm volatile("" ::: "memory");
    cb = (cb + 1 == 3) ? 0 : cb + 1;
  }

  #pragma unroll
  for (int n = 0; n < 4; ++n) {
    const int col = n0 + wc * 64 + n * 16 + l15;
    #pragma unroll
    for (int m = 0; m < 2; ++m) {
      #pragma unroll
      for (int r = 0; r < 4; ++r) {
        const int row = m0 + wr * 32 + m * 16 + l4 * 4 + r;
        if constexpr (EPI == 0) {
          const float val = (acc[m][n][r] + (bias ? bias[col] : 0.f)) * alpha;
          const int bb = row >> 11, ss = row & 2047, hh = col >> 6, dd = col & 63;
          ((u16*)outp)[(((size_t)(bb * 16 + hh)) * 2048 + ss) * 64 + dd] = f2bf(val);
        } else if constexpr (EPI == 1) {
          ((float*)outp)[(size_t)row * 1024 + col] = acc[m][n][r] + (bias ? bias[col] : 0.f);
        } else {  // EPI==2: V^T out [B*NH][64][2048]
          const float val = acc[m][n][r] + bias[row];
          const int hh = row >> 6, dd = row & 63, bb = col >> 11, ss = col & 2047;
          ((u16*)outp)[(((size_t)(bb * 16 + hh)) * 64 + dd) * 2048 + ss] = f2bf(val);
        }
      }
    }
  }
}

__global__ __launch_bounds__(512) void gemm_qkv(
    const u16* __restrict__ qbf, const u16* __restrict__ kvbf,
    const u16* __restrict__ wqb, const u16* __restrict__ wkb, const u16* __restrict__ wvb,
    const float* __restrict__ bq, const float* __restrict__ bv,
    u16* __restrict__ Qh, u16* __restrict__ Kh, u16* __restrict__ Vt)
{
  const int bid = blockIdx.x;
  const int swz = (bid & 7) * 32 + (bid >> 3);   // XCD-contiguous chunks
  const int which = blockIdx.y;
  if (which == 0)   // fold (1/sqrt(64)) * log2(e) into Q so attn can use exp2
    gemm_body<0>(qbf, wqb, bq, Qh, 0.125f * LOG2E, (swz >> 3) * 128, (swz & 7) * 128);
  else if (which == 1)
    gemm_body<0>(kvbf, wkb, nullptr, Kh, 1.0f, (swz >> 3) * 128, (swz & 7) * 128);
  else   // V^T = Wv * KV^T  (M=1024 d-rows, N=4096 s-cols)
    gemm_body<2>(wvb, kvbf, bv, Vt, 1.0f, (bid >> 5) * 128,
                 ((bid & 7) + ((bid >> 3) & 3) * 8) * 128);
}

__global__ __launch_bounds__(512) void gemm_fin(
    const u16* __restrict__ ctx, const u16* __restrict__ wob,
    const float* __restrict__ bo, float* __restrict__ out)
{
  const int bid = blockIdx.x;
  const int swz = (bid & 7) * 32 + (bid >> 3);
  gemm_body<1>(ctx, wob, bo, out, 1.0f, (swz >> 3) * 128, (swz & 7) * 128);
}

// ---------------- flash attention: dbuf-2, raw barriers, log2 softmax, mask-skip ----------------
// grid 512 XCD-chunked (4 heads/XCD). 128 q/block, 32 q/wave (2 groups of 16).
// S^T = K*Q^T (kv lane-local). Per-tile flag byte skips all mask work.
// l-sum computed by MFMA against a constant ones B-operand (lands row-indexed).
__global__ __launch_bounds__(256) void attn_kernel(
    const u16* __restrict__ Qh, const u16* __restrict__ Kh,
    const u16* __restrict__ Vt, const u16* __restrict__ am,
    const u8* __restrict__ flags, u16* __restrict__ ctx)
{
  __shared__ u16 Ks[2][4096];        // [64 kv][64 d] swizzled
  __shared__ u16 Vs[2][4096];        // [64 d][64 kv] swizzled
  __shared__ u16 Pl[4][2][1024];     // per wave per g: [16 q][64 kv] swizzled
  const int tid = threadIdx.x, wave = tid >> 6, lane = tid & 63;
  const int l15 = lane & 15, l4 = lane >> 4;
  const int x7 = l15 & 7;
  const int bid = blockIdx.x;
  const int pos = (bid & 7) * 64 + (bid >> 3);   // XCD-chunked (512 = 8*64)
  const int hh = pos >> 4, qt = pos & 15;
  const int b = hh >> 4, h = hh & 15;
  const int q0 = qt * 128;
  const u16* Qb = Qh + (size_t)hh * 2048 * 64;
  const u16* Kb = Kh + (size_t)hh * 2048 * 64;
  const u16* Vb = Vt + (size_t)hh * 64 * 2048;

  // tile-skip bitmask from flag bytes (uniform per block)
  u32 fbits = 0;
  {
    const u8* fb = flags + (b * 16 + qt) * 32;
    #pragma unroll
    for (int i = 0; i < 32; ++i) fbits |= (fb[i] ? 1u : 0u) << i;
  }

  // Q B-frags (col=q=l15, k=d=l4*8+j); 1/8*log2e folded at projection
  s16x8 qf[2][2];
  const u16* amrow[2];
  #pragma unroll
  for (int g = 0; g < 2; ++g) {
    const int qrow = q0 + wave * 32 + g * 16 + l15;
    qf[g][0] = *(const s16x8*)(Qb + (size_t)qrow * 64 + l4 * 8);
    qf[g][1] = *(const s16x8*)(Qb + (size_t)qrow * 64 + 32 + l4 * 8);
    amrow[g] = am + ((size_t)b * 2048 + qrow) * 2048;
  }

  const s16x8 ones = {16256, 16256, 16256, 16256, 16256, 16256, 16256, 16256}; // bf16 1.0

  // staging: 8-lane clusters cover one 128B row; slot XOR-swizzled via global src
  const int sr = wave * 16 + (lane >> 3);
  const int ss = ((lane & 7) ^ ((lane >> 3) & 7)) * 8;
  const u16* kS0 = Kb + (size_t)sr * 64 + ss;
  const u16* kS1 = Kb + (size_t)(sr + 8) * 64 + ss;
  const u16* vS0 = Vb + (size_t)sr * 2048 + ss;
  const u16* vS1 = Vb + (size_t)(sr + 8) * 2048 + ss;
  const int kd0 = wave * 1024, kd1 = kd0 + 512;

  auto stage = [&](int buf, int kt) {
    const int kv0 = kt * 64;
    gld16(kS0 + (size_t)kv0 * 64, &Ks[buf][kd0]);
    gld16(kS1 + (size_t)kv0 * 64, &Ks[buf][kd1]);
    gld16(vS0 + kv0, &Vs[buf][kd0]);
    gld16(vS1 + kv0, &Vs[buf][kd1]);
  };

  f32x4 of[2][4] = {};
  f32x4 lr[2] = {};                     // row-sum accumulators (C-layout rows)
  float m_run[2] = {-1e30f, -1e30f};

  stage(0, 0);
  asm volatile("s_waitcnt vmcnt(0)" ::: "memory");
  __builtin_amdgcn_s_barrier();
  asm volatile("" ::: "memory");

  int cur = 0;
  for (int kt = 0; kt < 32; ++kt) {
    if (kt < 31) stage(cur ^ 1, kt + 1);
    const int kv0 = kt * 64;
    const bool skip = (fbits >> kt) & 1u;

    ushort4 mk4[2][4];
    if (!skip) {
      #pragma unroll
      for (int g = 0; g < 2; ++g)
        #pragma unroll
        for (int nf = 0; nf < 4; ++nf)
          mk4[g][nf] = *(const ushort4*)(amrow[g] + kv0 + nf * 16 + l4 * 4);
    }

    // S^T = K * Q^T : lane holds q=l15, kv_local = nf*16 + l4*4 + r
    f32x4 sf[2][4];
    __builtin_amdgcn_s_setprio(1);
    #pragma unroll
    for (int nf = 0; nf < 4; ++nf) {
      const s16x8 ka0 = *(const s16x8*)&Ks[cur][nf * 1024 + l15 * 64 + ((l4 ^ x7) * 8)];
      const s16x8 ka1 = *(const s16x8*)&Ks[cur][nf * 1024 + l15 * 64 + (((4 + l4) ^ x7) * 8)];
      #pragma unroll
      for (int g = 0; g < 2; ++g) {
        f32x4 s = {0.f, 0.f, 0.f, 0.f};
        s = __builtin_amdgcn_mfma_f32_16x16x32_bf16(ka0, qf[g][0], s, 0, 0, 0);
        s = __builtin_amdgcn_mfma_f32_16x16x32_bf16(ka1, qf[g][1], s, 0, 0, 0);
        sf[g][nf] = s;
      }
    }
    __builtin_amdgcn_s_setprio(0);

    // online softmax per q-group (log2 domain, defer-max THR = 8 nats)
    #pragma unroll
    for (int g = 0; g < 2; ++g) {
      float tmax = -1e30f;
      #pragma unroll
      for (int nf = 0; nf < 4; ++nf)
        #pragma unroll
        for (int r = 0; r < 4; ++r) {
          float sv = sf[g][nf][r];
          if (!skip) sv += bf2f(((const u16*)&mk4[g][nf])[r]);
          sf[g][nf][r] = sv;
          tmax = fmaxf(tmax, sv);
        }
      tmax = fmaxf(tmax, __shfl_xor(tmax, 16));
      tmax = fmaxf(tmax, __shfl_xor(tmax, 32));

      const float mOld = m_run[g];
      float mn = mOld;
      if (!__all(tmax <= mOld + 11.54f)) {        // rescale path (rare after tile 0)
        mn = fmaxf(mOld, tmax);
        const float sc = exp2f(mOld - mn);
        m_run[g] = mn;
        float sq[4];
        #pragma unroll
        for (int r = 0; r < 4; ++r) sq[r] = __shfl(sc, l4 * 4 + r);
        #pragma unroll
        for (int r = 0; r < 4; ++r) lr[g][r] *= sq[r];
        #pragma unroll
        for (int nd = 0; nd < 4; ++nd)
          #pragma unroll
          for (int r = 0; r < 4; ++r) of[g][nd][r] *= sq[r];
      }

      u32* pw = (u32*)&Pl[wave][g][0];
      #pragma unroll
      for (int nf = 0; nf < 4; ++nf) {
        const float p0 = exp2f(sf[g][nf][0] - mn), p1 = exp2f(sf[g][nf][1] - mn);
        const float p2 = exp2f(sf[g][nf][2] - mn), p3 = exp2f(sf[g][nf][3] - mn);
        u32* w = pw + l15 * 32 + (((nf * 2 + (l4 >> 1)) ^ x7) * 4) + (l4 & 1) * 2;
        w[0] = cvtpk(p0, p1);
        w[1] = cvtpk(p2, p3);
      }
    }

    // O += P * V ; l += P * 1 (ones B-operand -> row-sums land row-indexed)
    __builtin_amdgcn_s_setprio(1);
    #pragma unroll
    for (int kh = 0; kh < 2; ++kh) {
      s16x8 pa[2];
      #pragma unroll
      for (int g = 0; g < 2; ++g)
        pa[g] = *(const s16x8*)&Pl[wave][g][l15 * 64 + (((kh * 4 + l4) ^ x7) * 8)];
      #pragma unroll
      for (int nd = 0; nd < 4; ++nd) {
        const s16x8 vb = *(const s16x8*)&Vs[cur][nd * 1024 + l15 * 64 + (((kh * 4 + l4) ^ x7) * 8)];
        #pragma unroll
        for (int g = 0; g < 2; ++g)
          of[g][nd] = __builtin_amdgcn_mfma_f32_16x16x32_bf16(pa[g], vb, of[g][nd], 0, 0, 0);
      }
      #pragma unroll
      for (int g = 0; g < 2; ++g)
        lr[g] = __builtin_amdgcn_mfma_f32_16x16x32_bf16(pa[g], ones, lr[g], 0, 0, 0);
    }
    __builtin_amdgcn_s_setprio(0);

    if (kt < 31) {
      asm volatile("s_waitcnt vmcnt(0)" ::: "memory");
      __builtin_amdgcn_s_barrier();
      asm volatile("" ::: "memory");
    }
    cur ^= 1;
  }

  // epilogue: normalize + write ctx [B][S][H] bf16 (lr already row-indexed)
  #pragma unroll
  for (int g = 0; g < 2; ++g) {
    #pragma unroll
    for (int r = 0; r < 4; ++r) {
      const float invq = 1.f / lr[g][r];
      const int qg = q0 + wave * 32 + g * 16 + l4 * 4 + r;
      const size_t rowbase = ((size_t)b * 2048 + qg) * 1024 + h * 64;
      #pragma unroll
      for (int nd = 0; nd < 4; ++nd)
        ctx[rowbase + nd * 16 + l15] = f2bf(of[g][nd][r] * invq);
    }
  }
}

// ---------------- launcher ----------------
extern "C" void kernel_launch(void* const* d_in, const int* in_sizes, int n_in,
                              void* d_out, int out_size, void* d_ws, size_t ws_size,
                              hipStream_t stream)
{
  const float* qs = (const float*)d_in[0];
  const float* kvs = (const float*)d_in[1];
  const float* mk = (const float*)d_in[2];
  const float* Wq = (const float*)d_in[3];
  const float* bq = (const float*)d_in[4];
  const float* Wk = (const float*)d_in[5];
  const float* Wv = (const float*)d_in[6];
  const float* bv = (const float*)d_in[7];
  const float* Wo = (const float*)d_in[8];
  const float* bo = (const float*)d_in[9];
  float* out = (float*)d_out;

  char* ws = (char*)d_ws;
  u16* q_bf  = (u16*)(ws + 0);
  u16* kv_bf = (u16*)(ws + 8388608);
  u16* wq_bf = (u16*)(ws + 16777216);
  u16* wk_bf = (u16*)(ws + 18874368);
  u16* wv_bf = (u16*)(ws + 20971520);
  u16* wo_bf = (u16*)(ws + 23068672);
  u16* am_bf = (u16*)(ws + 25165824);
  u16* Qhp   = (u16*)(ws + 41943040);   // [B*NH][2048][64]
  u16* Khp   = (u16*)(ws + 50331648);   // [B*NH][2048][64]
  u16* Vtp   = (u16*)(ws + 58720256);   // [B*NH][64][2048]  (pre-transposed)
  u16* ctxp  = (u16*)(ws + 67108864);   // [B][2048][1024]
  u8* flagsp = (u8*)wq_bf;              // 1 KB; wq_bf is dead after gemm_qkv

  prep_kernel<<<dim3(2048), dim3(256), 0, stream>>>(
      qs, kvs, mk, Wq, Wk, Wv, Wo, q_bf, kv_bf, am_bf, wq_bf, wk_bf, wv_bf, wo_bf);

  gemm_qkv<<<dim3(256, 3), dim3(512), 0, stream>>>(
      q_bf, kv_bf, wq_bf, wk_bf, wv_bf, bq, bv, Qhp, Khp, Vtp);

  flag_kernel<<<dim3(1024), dim3(256), 0, stream>>>(am_bf, flagsp);

  attn_kernel<<<dim3(512), dim3(256), 0, stream>>>(Qhp, Khp, Vtp, am_bf, flagsp, ctxp);

  gemm_fin<<<dim3(256), dim3(512), 0, stream>>>(ctxp, wo_bf, bo, out);
}